// Round 4
// baseline (336.650 us; speedup 1.0000x reference)
//
#include <hip/hip_runtime.h>
#include <hip/hip_bf16.h>
#include <math.h>

#define BATCH 8
#define LSEQ 2048
#define DIM 512
#define SK 40
#define NTOP 40

typedef __attribute__((ext_vector_type(8))) short bf16x8;
typedef __attribute__((ext_vector_type(4))) float f32x4;

// ---------------------------------------------------------------------------
// fp32 -> (hi, lo) bf16 split
__device__ inline void split1(float f, ushort& h, ushort& l) {
    __hip_bfloat16 bh = __float2bfloat16(f);
    float r = f - __bfloat162float(bh);
    __hip_bfloat16 bl = __float2bfloat16(r);
    h = *reinterpret_cast<ushort*>(&bh);
    l = *reinterpret_cast<ushort*>(&bl);
}

// one kernel: blocks [0,8192) convert x, blocks [8192,8960) convert the 3 W
__global__ __launch_bounds__(256) void convert_all(
    const float* __restrict__ x,
    const float* __restrict__ w0, const float* __restrict__ w1, const float* __restrict__ w2,
    ushort* __restrict__ xh, ushort* __restrict__ xl,
    ushort* __restrict__ wh, ushort* __restrict__ wl)
{
    const int bx = blockIdx.x;
    const float* src;
    ushort *dh, *dl;
    int i;
    if (bx < 8192) {
        i = (bx * 256 + (int)threadIdx.x) * 4;
        src = x; dh = xh; dl = xl;
    } else {
        const int j = bx - 8192;
        const int z = j >> 8;
        src = (z == 0) ? w0 : (z == 1) ? w1 : w2;
        dh = wh + (size_t)z * DIM * DIM;
        dl = wl + (size_t)z * DIM * DIM;
        i = ((j & 255) * 256 + (int)threadIdx.x) * 4;
    }
    float4 v = *reinterpret_cast<const float4*>(src + i);
    ushort4 h, l;
    split1(v.x, h.x, l.x); split1(v.y, h.y, l.y);
    split1(v.z, h.z, l.z); split1(v.w, h.w, l.w);
    *reinterpret_cast<ushort4*>(dh + i) = h;
    *reinterpret_cast<ushort4*>(dl + i) = l;
}

// ---------------------------------------------------------------------------
__device__ inline void load_lds16(const void* g, void* l) {
    __builtin_amdgcn_global_load_lds(
        (const __attribute__((address_space(1))) void*)g,
        (__attribute__((address_space(3))) void*)l, 16, 0, 0);
}

// 8-phase 256x128 GEMM, K=1536 virtual:  C = [xh|xl|xh] . [Wh|Wh|Wl]^T
// tile t (0..23): third tt=t>>3 selects source planes, ksub=(t&7)*64.
// LDS: A 256x64 (2 k-chunks of 256x32), B 128x64 (2 of 128x32), double-buffered.
// chunk = A(2 loads/thr) + B(1 load/thr) = 3 vm-instr; 2 chunks in flight -> vmcnt(6).
__global__ __launch_bounds__(512) void gemm8(
    const ushort* __restrict__ xh, const ushort* __restrict__ xl,
    const ushort* __restrict__ whAll, const ushort* __restrict__ wlAll,
    float* __restrict__ Q, float* __restrict__ K, float* __restrict__ V)
{
    __shared__ ushort SA[32768];   // 2 buf x 2 ks x 256x32
    __shared__ ushort SB[16384];   // 2 buf x 2 ks x 128x32

    const int tid  = threadIdx.x;
    const int lane = tid & 63;
    const int w    = tid >> 6;
    const int wr   = w >> 1;      // 0..3  (64-row band)
    const int wcn  = w & 1;       // 0..1  (64-col band)

    // XCD-bijective swizzle (768 % 8 == 0), nb-minor so consecutive wg share A panel
    const int wg = ((int)blockIdx.x & 7) * 96 + ((int)blockIdx.x >> 3);
    const int mb = wg / 12, nb = wg % 12;
    const int z  = nb >> 2;
    float* C = (z == 0) ? Q : (z == 1) ? K : V;
    const int row0  = mb * 256;
    const int wrow0 = (nb & 3) * 128;
    const ushort* whb = whAll + (size_t)z * (DIM * DIM);
    const ushort* wlb = wlAll + (size_t)z * (DIM * DIM);

    // staging invariants (per thread)
    int rA[2], dA[2]; size_t sA[2];
    #pragma unroll
    for (int i = 0; i < 2; ++i) {
        const int g = i * 512 + tid;
        const int row = g >> 2, sl = g & 3;
        const int ss = sl ^ ((row >> 1) & 3);
        rA[i] = row;
        dA[i] = (g & ~63) * 8;
        sA[i] = (size_t)(row0 + row) * DIM + ss * 8;
    }
    int dB; size_t sB;
    {
        const int g = tid;
        const int row = g >> 2, sl = g & 3;
        const int ss = sl ^ ((row >> 1) & 3);
        dB = (g & ~63) * 8;
        sB = (size_t)(wrow0 + row) * DIM + ss * 8;
    }

    // fragment read offsets (elements), invariant across tiles
    int aoff[4], boff[4];
    #pragma unroll
    for (int mf = 0; mf < 4; ++mf) {
        const int row = wr * 64 + mf * 16 + (lane & 15);
        aoff[mf] = row * 32 + (((lane >> 4) ^ ((row >> 1) & 3)) * 8);
    }
    #pragma unroll
    for (int nf = 0; nf < 4; ++nf) {
        const int row = wcn * 64 + nf * 16 + (lane & 15);
        boff[nf] = row * 32 + (((lane >> 4) ^ ((row >> 1) & 3)) * 8);
    }

    f32x4 acc[4][4];
    #pragma unroll
    for (int i = 0; i < 4; ++i)
        #pragma unroll
        for (int j = 0; j < 4; ++j)
            acc[i][j] = (f32x4){0.f, 0.f, 0.f, 0.f};

#define STAGE_CHUNK(t_, ks_, cb_)                                              \
    {                                                                          \
        const int tt_ = (t_) >> 3;                                             \
        const int ksrc_ = (((t_) & 7) << 6) + ((ks_) << 5);                    \
        const ushort* ap_ = (tt_ == 1) ? xl : xh;                              \
        const ushort* bp_ = (tt_ == 2) ? wlb : whb;                            \
        const int ab_ = ((cb_) * 2 + (ks_)) * 8192;                            \
        const int bb_ = ((cb_) * 2 + (ks_)) * 4096;                            \
        load_lds16(ap_ + sA[0] + ksrc_, &SA[ab_ + dA[0]]);                     \
        load_lds16(ap_ + sA[1] + ksrc_, &SA[ab_ + dA[1]]);                     \
        load_lds16(bp_ + sB + ksrc_,    &SB[bb_ + dB]);                        \
    }

    // prologue: k0(0), k1(0), k0(1); keep 2 chunks in flight
    STAGE_CHUNK(0, 0, 0)
    STAGE_CHUNK(0, 1, 0)
    STAGE_CHUNK(1, 0, 1)
    asm volatile("s_waitcnt vmcnt(6)" ::: "memory");
    asm volatile("s_barrier" ::: "memory");

    #pragma unroll 2
    for (int t = 0; t < 24; ++t) {
        const int cb = t & 1;
        // ---------------- phase 0 (ks = 0) ----------------
        {
            bf16x8 af[4], bf_[4];
            const int ab = (cb * 2 + 0) * 8192;
            const int bb = (cb * 2 + 0) * 4096;
            #pragma unroll
            for (int mf = 0; mf < 4; ++mf)
                af[mf] = *reinterpret_cast<const bf16x8*>(&SA[ab + aoff[mf]]);
            #pragma unroll
            for (int nf = 0; nf < 4; ++nf)
                bf_[nf] = *reinterpret_cast<const bf16x8*>(&SB[bb + boff[nf]]);
            if (t + 1 < 24) STAGE_CHUNK(t + 1, 1, cb ^ 1)
            asm volatile("s_waitcnt vmcnt(6)" ::: "memory");
            asm volatile("s_barrier" ::: "memory");
            __builtin_amdgcn_s_setprio(1);
            #pragma unroll
            for (int mf = 0; mf < 4; ++mf)
                #pragma unroll
                for (int nf = 0; nf < 4; ++nf)
                    acc[mf][nf] = __builtin_amdgcn_mfma_f32_16x16x32_bf16(
                        af[mf], bf_[nf], acc[mf][nf], 0, 0, 0);
            __builtin_amdgcn_s_setprio(0);
            asm volatile("s_barrier" ::: "memory");
        }
        // ---------------- phase 1 (ks = 1) ----------------
        {
            bf16x8 af[4], bf_[4];
            const int ab = (cb * 2 + 1) * 8192;
            const int bb = (cb * 2 + 1) * 4096;
            #pragma unroll
            for (int mf = 0; mf < 4; ++mf)
                af[mf] = *reinterpret_cast<const bf16x8*>(&SA[ab + aoff[mf]]);
            #pragma unroll
            for (int nf = 0; nf < 4; ++nf)
                bf_[nf] = *reinterpret_cast<const bf16x8*>(&SB[bb + boff[nf]]);
            if (t + 2 < 24) STAGE_CHUNK(t + 2, 0, cb)
            asm volatile("s_waitcnt vmcnt(6)" ::: "memory");
            asm volatile("s_barrier" ::: "memory");
            __builtin_amdgcn_s_setprio(1);
            #pragma unroll
            for (int mf = 0; mf < 4; ++mf)
                #pragma unroll
                for (int nf = 0; nf < 4; ++nf)
                    acc[mf][nf] = __builtin_amdgcn_mfma_f32_16x16x32_bf16(
                        af[mf], bf_[nf], acc[mf][nf], 0, 0, 0);
            __builtin_amdgcn_s_setprio(0);
            asm volatile("s_barrier" ::: "memory");
        }
    }
#undef STAGE_CHUNK

    #pragma unroll
    for (int mf = 0; mf < 4; ++mf)
        #pragma unroll
        for (int nf = 0; nf < 4; ++nf) {
            float* cp = C + (size_t)(row0 + wr * 64 + mf * 16 + (lane >> 4) * 4) * DIM
                          + wrow0 + wcn * 64 + nf * 16 + (lane & 15);
            #pragma unroll
            for (int j = 0; j < 4; ++j)
                cp[(size_t)j * DIM] = acc[mf][nf][j];
        }
}

// ---------------------------------------------------------------------------
// fallback fp32 GEMM (round-1, proven)
#define BM 64
#define BN 64
#define BKD 32
__global__ __launch_bounds__(256) void gemm_qkv(
    const float* __restrict__ x,
    const float* __restrict__ Wq, const float* __restrict__ Wk, const float* __restrict__ Wv,
    float* __restrict__ Q, float* __restrict__ K, float* __restrict__ V)
{
    const float* W;
    float* C;
    if (blockIdx.z == 0)      { W = Wq; C = Q; }
    else if (blockIdx.z == 1) { W = Wk; C = K; }
    else                      { W = Wv; C = V; }

    __shared__ float As[BKD][BM];
    __shared__ float Bs[BKD][BN];

    const int tid  = threadIdx.x;
    const int row0 = blockIdx.x * BM;
    const int col0 = blockIdx.y * BN;
    const int ty   = tid >> 4;
    const int tx   = tid & 15;
    const int lrow = tid >> 3;
    const int lkq  = tid & 7;

    float acc[4][4] = {};
    for (int k0 = 0; k0 < DIM; k0 += BKD) {
        #pragma unroll
        for (int h = 0; h < 2; ++h) {
            const int arow = lrow + h * 32;
            float4 va = *reinterpret_cast<const float4*>(&x[(size_t)(row0 + arow) * DIM + k0 + lkq * 4]);
            As[lkq * 4 + 0][arow] = va.x; As[lkq * 4 + 1][arow] = va.y;
            As[lkq * 4 + 2][arow] = va.z; As[lkq * 4 + 3][arow] = va.w;
            float4 vb = *reinterpret_cast<const float4*>(&W[(size_t)(col0 + arow) * DIM + k0 + lkq * 4]);
            Bs[lkq * 4 + 0][arow] = vb.x; Bs[lkq * 4 + 1][arow] = vb.y;
            Bs[lkq * 4 + 2][arow] = vb.z; Bs[lkq * 4 + 3][arow] = vb.w;
        }
        __syncthreads();
        #pragma unroll
        for (int kk = 0; kk < BKD; ++kk) {
            float4 a4 = *reinterpret_cast<const float4*>(&As[kk][ty * 4]);
            float4 b4 = *reinterpret_cast<const float4*>(&Bs[kk][tx * 4]);
            float af[4] = {a4.x, a4.y, a4.z, a4.w};
            float bf[4] = {b4.x, b4.y, b4.z, b4.w};
            #pragma unroll
            for (int i = 0; i < 4; ++i)
                #pragma unroll
                for (int j = 0; j < 4; ++j)
                    acc[i][j] += af[i] * bf[j];
        }
        __syncthreads();
    }
    #pragma unroll
    for (int i = 0; i < 4; ++i) {
        float4 o = make_float4(acc[i][0], acc[i][1], acc[i][2], acc[i][3]);
        *reinterpret_cast<float4*>(&C[(size_t)(row0 + ty * 4 + i) * DIM + col0 + tx * 4]) = o;
    }
}

// ---------------------------------------------------------------------------
__global__ __launch_bounds__(256) void compute_m(
    const float* __restrict__ Q, const float* __restrict__ K,
    const int* __restrict__ smp, float* __restrict__ M)
{
    const int wv   = threadIdx.x >> 6;
    const int lane = threadIdx.x & 63;
    const int b    = blockIdx.x & 7;
    const int l    = (blockIdx.x >> 3) * 4 + wv;

    const float* qr = Q + ((size_t)b * LSEQ + l) * DIM;
    float4 q0 = *reinterpret_cast<const float4*>(&qr[lane * 8]);
    float4 q1 = *reinterpret_cast<const float4*>(&qr[lane * 8 + 4]);

    const int* sp = smp + l * SK;
    const float* Kb = K + (size_t)b * LSEQ * DIM;

    float mx = -1e30f, sm = 0.0f;
    for (int s = 0; s < SK; s += 4) {
        int4 id = *reinterpret_cast<const int4*>(sp + s);
        const float* r0 = Kb + (size_t)id.x * DIM + lane * 8;
        const float* r1 = Kb + (size_t)id.y * DIM + lane * 8;
        const float* r2 = Kb + (size_t)id.z * DIM + lane * 8;
        const float* r3 = Kb + (size_t)id.w * DIM + lane * 8;
        float4 a0 = *reinterpret_cast<const float4*>(r0);
        float4 a1 = *reinterpret_cast<const float4*>(r0 + 4);
        float4 b0 = *reinterpret_cast<const float4*>(r1);
        float4 b1 = *reinterpret_cast<const float4*>(r1 + 4);
        float4 c0 = *reinterpret_cast<const float4*>(r2);
        float4 c1 = *reinterpret_cast<const float4*>(r2 + 4);
        float4 d0 = *reinterpret_cast<const float4*>(r3);
        float4 d1 = *reinterpret_cast<const float4*>(r3 + 4);

        float p0 = q0.x*a0.x + q0.y*a0.y + q0.z*a0.z + q0.w*a0.w
                 + q1.x*a1.x + q1.y*a1.y + q1.z*a1.z + q1.w*a1.w;
        float p1 = q0.x*b0.x + q0.y*b0.y + q0.z*b0.z + q0.w*b0.w
                 + q1.x*b1.x + q1.y*b1.y + q1.z*b1.z + q1.w*b1.w;
        float p2 = q0.x*c0.x + q0.y*c0.y + q0.z*c0.z + q0.w*c0.w
                 + q1.x*c1.x + q1.y*c1.y + q1.z*c1.z + q1.w*c1.w;
        float p3 = q0.x*d0.x + q0.y*d0.y + q0.z*d0.z + q0.w*d0.w
                 + q1.x*d1.x + q1.y*d1.y + q1.z*d1.z + q1.w*d1.w;
        #pragma unroll
        for (int o = 32; o; o >>= 1) {
            p0 += __shfl_xor(p0, o, 64);
            p1 += __shfl_xor(p1, o, 64);
            p2 += __shfl_xor(p2, o, 64);
            p3 += __shfl_xor(p3, o, 64);
        }
        mx = fmaxf(mx, fmaxf(fmaxf(p0, p1), fmaxf(p2, p3)));
        sm += (p0 + p1) + (p2 + p3);
    }
    if (lane == 0) M[(size_t)b * LSEQ + l] = mx - sm * (1.0f / LSEQ);
}

// ---------------------------------------------------------------------------
__global__ __launch_bounds__(1024) void topk_kernel(
    const float* __restrict__ M, int* __restrict__ topidx)
{
    const int b = blockIdx.x;
    __shared__ float vals[LSEQ];
    __shared__ float wv[16];
    __shared__ int   wi[16];
    const int tid  = threadIdx.x;
    const int lane = tid & 63;
    const int wave = tid >> 6;

    vals[tid]        = M[b * LSEQ + tid];
    vals[tid + 1024] = M[b * LSEQ + tid + 1024];
    __syncthreads();

    for (int t = 0; t < NTOP; ++t) {
        float v0 = vals[tid], v1 = vals[tid + 1024];
        float bv; int bi;
        if (v0 >= v1) { bv = v0; bi = tid; } else { bv = v1; bi = tid + 1024; }
        #pragma unroll
        for (int o = 32; o; o >>= 1) {
            float ov = __shfl_xor(bv, o, 64);
            int   oi = __shfl_xor(bi, o, 64);
            if (ov > bv || (ov == bv && oi < bi)) { bv = ov; bi = oi; }
        }
        if (lane == 0) { wv[wave] = bv; wi[wave] = bi; }
        __syncthreads();
        if (wave == 0) {
            float fv = (lane < 16) ? wv[lane] : -1e30f;
            int   fi = (lane < 16) ? wi[lane] : 0x7fffffff;
            #pragma unroll
            for (int o = 8; o; o >>= 1) {
                float ov = __shfl_xor(fv, o, 64);
                int   oi = __shfl_xor(fi, o, 64);
                if (ov > fv || (ov == fv && oi < fi)) { fv = ov; fi = oi; }
            }
            if (lane == 0) {
                topidx[b * NTOP + t] = fi;
                vals[fi] = -1e30f;
            }
        }
        __syncthreads();
    }
}

__global__ __launch_bounds__(256) void vmean_partial(
    const float* __restrict__ V, float* __restrict__ P)
{
    const int b = blockIdx.x & 7, c = blockIdx.x >> 3;
    const int tid = threadIdx.x;
    #pragma unroll
    for (int dd = 0; dd < 2; ++dd) {
        const int d = tid + dd * 256;
        const float* vp = V + ((size_t)b * LSEQ + c * 128) * DIM + d;
        float s = 0.0f;
        for (int r = 0; r < 128; ++r) s += vp[(size_t)r * DIM];
        P[(size_t)(b * 16 + c) * DIM + d] = s;
    }
}

__global__ __launch_bounds__(256) void vmean_reduce(
    const float* __restrict__ P, float* __restrict__ vmean)
{
    const int b = blockIdx.x;
    const int tid = threadIdx.x;
    #pragma unroll
    for (int dd = 0; dd < 2; ++dd) {
        const int d = tid + dd * 256;
        float s = 0.0f;
        #pragma unroll
        for (int c = 0; c < 16; ++c) s += P[(size_t)(b * 16 + c) * DIM + d];
        vmean[b * DIM + d] = s * (1.0f / LSEQ);
    }
}

__global__ __launch_bounds__(256) void fill_out(
    const float4* __restrict__ vmean4, float4* __restrict__ out4)
{
    const int f = blockIdx.x * 256 + threadIdx.x;
    const int d4 = f & 127;
    const int b  = f >> 18;
    out4[f] = vmean4[b * 128 + d4];
}

// ---------------------------------------------------------------------------
__global__ __launch_bounds__(256) void scores_kernel(
    const float* __restrict__ Q, const float* __restrict__ K,
    const int* __restrict__ topidx, float* __restrict__ S)
{
    const int b  = blockIdx.x & 7;
    const int lc = blockIdx.x >> 3;           // 64-key chunk, 0..31
    __shared__ float Qs[40 * 132];
    __shared__ float Ks[64 * 132];
    __shared__ int tix[NTOP];
    const int tid = threadIdx.x;
    const int lt  = tid & 31;
    const int ug  = tid >> 5;
    float acc[2][5] = {};

    if (tid < NTOP) tix[tid] = topidx[b * NTOP + tid];
    __syncthreads();

    for (int d0 = 0; d0 < DIM; d0 += 128) {
        for (int j = tid; j < 1280; j += 256) {
            const int u = j >> 5, d4 = j & 31;
            *reinterpret_cast<float4*>(&Qs[u * 132 + d4 * 4]) =
                *reinterpret_cast<const float4*>(&Q[((size_t)b * LSEQ + tix[u]) * DIM + d0 + d4 * 4]);
        }
        for (int j = tid; j < 2048; j += 256) {
            const int l = j >> 5, d4 = j & 31;
            *reinterpret_cast<float4*>(&Ks[l * 132 + d4 * 4]) =
                *reinterpret_cast<const float4*>(&K[((size_t)b * LSEQ + lc * 64 + l) * DIM + d0 + d4 * 4]);
        }
        __syncthreads();
        for (int d4 = 0; d4 < 32; ++d4) {
            float4 ka = *reinterpret_cast<const float4*>(&Ks[lt * 132 + d4 * 4]);
            float4 kb = *reinterpret_cast<const float4*>(&Ks[(lt + 32) * 132 + d4 * 4]);
            #pragma unroll
            for (int i = 0; i < 5; ++i) {
                float4 q = *reinterpret_cast<const float4*>(&Qs[(ug + i * 8) * 132 + d4 * 4]);
                acc[0][i] += q.x * ka.x + q.y * ka.y + q.z * ka.z + q.w * ka.w;
                acc[1][i] += q.x * kb.x + q.y * kb.y + q.z * kb.z + q.w * kb.w;
            }
        }
        __syncthreads();
    }
    const float scale = 0.044194173824159216f;
    #pragma unroll
    for (int i = 0; i < 5; ++i) {
        const int u = ug + i * 8;
        S[((size_t)(b * NTOP + u)) * LSEQ + lc * 64 + lt]      = acc[0][i] * scale;
        S[((size_t)(b * NTOP + u)) * LSEQ + lc * 64 + lt + 32] = acc[1][i] * scale;
    }
}

__global__ __launch_bounds__(256) void softmax_kernel(
    const float* __restrict__ S, float* __restrict__ Pt)
{
    const int row = blockIdx.x;
    const int b = row / NTOP, u = row % NTOP;
    __shared__ float red[4];
    const int tid  = threadIdx.x;
    const int lane = tid & 63;
    const int wave = tid >> 6;
    const float* sr = S + (size_t)row * LSEQ;

    float v[8];
    float mx = -1e30f;
    #pragma unroll
    for (int j = 0; j < 8; ++j) { v[j] = sr[tid + j * 256]; mx = fmaxf(mx, v[j]); }
    #pragma unroll
    for (int o = 32; o; o >>= 1) mx = fmaxf(mx, __shfl_xor(mx, o, 64));
    if (lane == 0) red[wave] = mx;
    __syncthreads();
    mx = fmaxf(fmaxf(red[0], red[1]), fmaxf(red[2], red[3]));
    __syncthreads();

    float s = 0.0f;
    #pragma unroll
    for (int j = 0; j < 8; ++j) { v[j] = __expf(v[j] - mx); s += v[j]; }
    #pragma unroll
    for (int o = 32; o; o >>= 1) s += __shfl_xor(s, o, 64);
    if (lane == 0) red[wave] = s;
    __syncthreads();
    const float rec = 1.0f / (red[0] + red[1] + red[2] + red[3]);

    #pragma unroll
    for (int j = 0; j < 8; ++j)
        Pt[((size_t)b * LSEQ + tid + j * 256) * NTOP + u] = v[j] * rec;
}

__global__ __launch_bounds__(512) void pv_partial(
    const float* __restrict__ Pt, const float* __restrict__ V, float* __restrict__ Ppart)
{
    const int b  = blockIdx.x & 7;
    const int lc = blockIdx.x >> 3;           // 0..15, 128 keys each
    const int d  = threadIdx.x;
    float part[NTOP] = {};
    for (int l = 0; l < 128; ++l) {
        const float v = V[((size_t)b * LSEQ + lc * 128 + l) * DIM + d];
        const float* ps = Pt + ((size_t)b * LSEQ + lc * 128 + l) * NTOP;
        #pragma unroll
        for (int u = 0; u < NTOP; ++u) part[u] = fmaf(ps[u], v, part[u]);
    }
    #pragma unroll
    for (int u = 0; u < NTOP; ++u)
        Ppart[(((size_t)(b * 16 + lc)) * NTOP + u) * DIM + d] = part[u];
}

__global__ __launch_bounds__(512) void pv_reduce(
    const float* __restrict__ Ppart, const int* __restrict__ topidx, float* __restrict__ out)
{
    const int row = blockIdx.x;
    const int b = row / NTOP, u = row % NTOP;
    const int d = threadIdx.x;
    float s = 0.0f;
    #pragma unroll
    for (int lc = 0; lc < 16; ++lc)
        s += Ppart[(((size_t)(b * 16 + lc)) * NTOP + u) * DIM + d];
    out[((size_t)b * LSEQ + topidx[row]) * DIM + d] = s;
}

// ---------------------------------------------------------------------------
// round-1 attention (fallback only)
__global__ __launch_bounds__(256) void att_kernel(
    const float* __restrict__ Q, const float* __restrict__ K, const float* __restrict__ V,
    const int* __restrict__ topidx, float* __restrict__ out)
{
    const int b = blockIdx.x / NTOP;
    const int u = blockIdx.x % NTOP;
    const int l0 = topidx[b * NTOP + u];

    __shared__ float p[LSEQ];
    __shared__ float redm[4];
    __shared__ float reds[4];

    const int tid  = threadIdx.x;
    const int lane = tid & 63;
    const int wave = tid >> 6;

    const float* qr = Q + ((size_t)b * LSEQ + l0) * DIM;
    float4 q0 = *reinterpret_cast<const float4*>(&qr[lane * 8]);
    float4 q1 = *reinterpret_cast<const float4*>(&qr[lane * 8 + 4]);
    const float scale = 0.044194173824159216f;

    for (int it = 0; it < 512; ++it) {
        const int l = wave * 512 + it;
        const float* kr = K + ((size_t)b * LSEQ + l) * DIM;
        float4 k0 = *reinterpret_cast<const float4*>(&kr[lane * 8]);
        float4 k1 = *reinterpret_cast<const float4*>(&kr[lane * 8 + 4]);
        float d = q0.x * k0.x + q0.y * k0.y + q0.z * k0.z + q0.w * k0.w
                + q1.x * k1.x + q1.y * k1.y + q1.z * k1.z + q1.w * k1.w;
        #pragma unroll
        for (int o = 32; o; o >>= 1) d += __shfl_xor(d, o, 64);
        if (lane == 0) p[l] = d * scale;
    }
    __syncthreads();

    float mx = -1e30f;
    for (int i = tid; i < LSEQ; i += 256) mx = fmaxf(mx, p[i]);
    #pragma unroll
    for (int o = 32; o; o >>= 1) mx = fmaxf(mx, __shfl_xor(mx, o, 64));
    if (lane == 0) redm[wave] = mx;
    __syncthreads();
    mx = fmaxf(fmaxf(redm[0], redm[1]), fmaxf(redm[2], redm[3]));

    float s = 0.0f;
    for (int i = tid; i < LSEQ; i += 256) {
        float e = __expf(p[i] - mx);
        s += e;
        p[i] = e;
    }
    #pragma unroll
    for (int o = 32; o; o >>= 1) s += __shfl_xor(s, o, 64);
    if (lane == 0) reds[wave] = s;
    __syncthreads();
    const float rec = 1.0f / (reds[0] + reds[1] + reds[2] + reds[3]);

    float s0 = 0.0f, s1 = 0.0f;
    const float* vp = V + (size_t)b * LSEQ * DIM;
    for (int l = 0; l < LSEQ; ++l) {
        const float w = p[l];
        s0 += w * vp[(size_t)l * DIM + tid];
        s1 += w * vp[(size_t)l * DIM + tid + 256];
    }
    float* orow = out + ((size_t)b * LSEQ + l0) * DIM;
    orow[tid]       = s0 * rec;
    orow[tid + 256] = s1 * rec;
}

// ---------------------------------------------------------------------------
extern "C" void kernel_launch(void* const* d_in, const int* in_sizes, int n_in,
                              void* d_out, int out_size, void* d_ws, size_t ws_size,
                              hipStream_t stream)
{
    const float* x   = (const float*)d_in[0];
    const float* Wq  = (const float*)d_in[1];
    const float* Wk  = (const float*)d_in[2];
    const float* Wv  = (const float*)d_in[3];
    const int*   smp = (const int*)d_in[4];
    float* out = (float*)d_out;

    const size_t NQKV = (size_t)BATCH * LSEQ * DIM;   // 8388608
    float* ws = (float*)d_ws;

    float* Q     = ws;
    float* K     = Q + NQKV;
    float* V     = K + NQKV;
    float* Mb    = V + NQKV;                 // 16384
    float* vmP   = Mb + BATCH * LSEQ;        // 65536
    float* vmean = vmP + BATCH * 16 * DIM;   // 4096
    float* S     = vmean + BATCH * DIM;      // 655360
    float* Pt    = S + (size_t)BATCH * NTOP * LSEQ;   // 655360
    float* Qsel  = Pt + (size_t)BATCH * NTOP * LSEQ;  // 163840 (reserved)
    float* Ppart = Qsel + (size_t)BATCH * NTOP * DIM; // 2621440
    int*   topidx = (int*)(Ppart + (size_t)BATCH * 16 * NTOP * DIM);
    ushort* xh = (ushort*)(topidx + BATCH * NTOP);
    ushort* xl = xh + NQKV;
    ushort* wh = xl + NQKV;
    ushort* wl = wh + (size_t)3 * DIM * DIM;
    const size_t need_fast = (size_t)((char*)(wl + (size_t)3 * DIM * DIM) - (char*)d_ws);
    const size_t need_mid  = (size_t)((char*)(topidx + BATCH * NTOP) - (char*)d_ws);

    const bool fast = ws_size >= need_fast;
    const bool mid  = ws_size >= need_mid;

    if (mid) {
        if (fast) {
            convert_all<<<8960, 256, 0, stream>>>(x, Wq, Wk, Wv, xh, xl, wh, wl);
            gemm8<<<768, 512, 0, stream>>>(xh, xl, wh, wl, Q, K, V);
        } else {
            gemm_qkv<<<dim3(BATCH * LSEQ / BM, DIM / BN, 3), 256, 0, stream>>>(
                x, Wq, Wk, Wv, Q, K, V);
        }
        compute_m<<<4096, 256, 0, stream>>>(Q, K, smp, Mb);
        topk_kernel<<<BATCH, 1024, 0, stream>>>(Mb, topidx);
        vmean_partial<<<BATCH * 16, 256, 0, stream>>>(V, vmP);
        vmean_reduce<<<BATCH, 256, 0, stream>>>(vmP, vmean);
        fill_out<<<(BATCH * LSEQ * DIM / 4) / 256, 256, 0, stream>>>(
            (const float4*)vmean, (float4*)out);
        scores_kernel<<<256, 256, 0, stream>>>(Q, K, topidx, S);
        softmax_kernel<<<BATCH * NTOP, 256, 0, stream>>>(S, Pt);
        pv_partial<<<128, 512, 0, stream>>>(Pt, V, Ppart);
        pv_reduce<<<BATCH * NTOP, 512, 0, stream>>>(Ppart, topidx, out);
    } else {
        float* Qf = ws;
        float* Kf = Qf + NQKV;
        float* Vf = Kf + NQKV;
        float* Mf = Vf + NQKV;
        int*   ti = (int*)(Mf + (size_t)BATCH * LSEQ);
        float* Pf = (float*)(ti + BATCH * NTOP);
        float* vm = Pf + (size_t)BATCH * 16 * DIM;

        gemm_qkv<<<dim3(BATCH * LSEQ / BM, DIM / BN, 3), 256, 0, stream>>>(
            x, Wq, Wk, Wv, Qf, Kf, Vf);
        compute_m<<<4096, 256, 0, stream>>>(Qf, Kf, smp, Mf);
        topk_kernel<<<BATCH, 1024, 0, stream>>>(Mf, ti);
        vmean_partial<<<BATCH * 16, 256, 0, stream>>>(Vf, Pf);
        vmean_reduce<<<BATCH, 256, 0, stream>>>(Pf, vm);
        fill_out<<<(BATCH * LSEQ * DIM / 4) / 256, 256, 0, stream>>>(
            (const float4*)vm, (float4*)out);
        att_kernel<<<BATCH * NTOP, 256, 0, stream>>>(Qf, Kf, Vf, ti, out);
    }
}

// Round 5
// 306.602 us; speedup vs baseline: 1.0980x; 1.0980x over previous
//
#include <hip/hip_runtime.h>
#include <hip/hip_bf16.h>
#include <math.h>

#define BATCH 8
#define LSEQ 2048
#define DIM 512
#define SK 40
#define NTOP 40

typedef __attribute__((ext_vector_type(8))) short bf16x8;
typedef __attribute__((ext_vector_type(4))) float f32x4;

// ---------------------------------------------------------------------------
// fp32 -> (hi, lo) bf16 split
__device__ inline void split1(float f, ushort& h, ushort& l) {
    __hip_bfloat16 bh = __float2bfloat16(f);
    float r = f - __bfloat162float(bh);
    __hip_bfloat16 bl = __float2bfloat16(r);
    h = *reinterpret_cast<ushort*>(&bh);
    l = *reinterpret_cast<ushort*>(&bl);
}

// one kernel: blocks [0,8192) convert x, blocks [8192,8960) convert the 3 W
__global__ __launch_bounds__(256) void convert_all(
    const float* __restrict__ x,
    const float* __restrict__ w0, const float* __restrict__ w1, const float* __restrict__ w2,
    ushort* __restrict__ xh, ushort* __restrict__ xl,
    ushort* __restrict__ wh, ushort* __restrict__ wl)
{
    const int bx = blockIdx.x;
    const float* src;
    ushort *dh, *dl;
    int i;
    if (bx < 8192) {
        i = (bx * 256 + (int)threadIdx.x) * 4;
        src = x; dh = xh; dl = xl;
    } else {
        const int j = bx - 8192;
        const int z = j >> 8;
        src = (z == 0) ? w0 : (z == 1) ? w1 : w2;
        dh = wh + (size_t)z * DIM * DIM;
        dl = wl + (size_t)z * DIM * DIM;
        i = ((j & 255) * 256 + (int)threadIdx.x) * 4;
    }
    float4 v = *reinterpret_cast<const float4*>(src + i);
    ushort4 h, l;
    split1(v.x, h.x, l.x); split1(v.y, h.y, l.y);
    split1(v.z, h.z, l.z); split1(v.w, h.w, l.w);
    *reinterpret_cast<ushort4*>(dh + i) = h;
    *reinterpret_cast<ushort4*>(dl + i) = l;
}

// ---------------------------------------------------------------------------
// split-bf16 MFMA GEMM: C[m,n] = sum_k A[m,k]*W[n,k], 128x128 tile, BK=32
// (round-3 proven kernel: 84 us, MfmaUtil 40%, 0 bank conflicts)
__device__ inline void load_lds16(const void* g, void* l) {
    __builtin_amdgcn_global_load_lds(
        (const __attribute__((address_space(1))) void*)g,
        (__attribute__((address_space(3))) void*)l, 16, 0, 0);
}

__global__ __launch_bounds__(256) void gemm_mfma(
    const ushort* __restrict__ xh, const ushort* __restrict__ xl,
    const ushort* __restrict__ whAll, const ushort* __restrict__ wlAll,
    float* __restrict__ Q, float* __restrict__ K, float* __restrict__ V)
{
    const ushort* Wh = whAll + (size_t)blockIdx.z * DIM * DIM;
    const ushort* Wl = wlAll + (size_t)blockIdx.z * DIM * DIM;
    float* C = (blockIdx.z == 0) ? Q : (blockIdx.z == 1) ? K : V;

    __shared__ ushort Ah[128 * 32], Al[128 * 32], Bh[128 * 32], Bl[128 * 32];

    const int tid  = threadIdx.x;
    const int lane = tid & 63;
    const int w    = tid >> 6;
    const int row0 = blockIdx.x * 128;
    const int col0 = blockIdx.y * 128;
    const int wr = w >> 1, wc = w & 1;

    const int rA  = w * 16 + (lane >> 2);
    const int sh_ = (lane & 3) ^ ((rA >> 1) & 3);
    const size_t aoff = (size_t)(row0 + rA) * DIM + sh_ * 8;
    const size_t boff = (size_t)(col0 + rA) * DIM + sh_ * 8;

    f32x4 acc[4][4];
    #pragma unroll
    for (int i = 0; i < 4; ++i)
        #pragma unroll
        for (int j = 0; j < 4; ++j)
            acc[i][j] = (f32x4){0.f, 0.f, 0.f, 0.f};

    const int rbA = wr * 64 + (lane & 15);
    const int rbB = wc * 64 + (lane & 15);
    const int kh  = lane >> 4;

    for (int k0 = 0; k0 < DIM; k0 += 32) {
        load_lds16(xh + aoff + k0,            &Ah[w * 512]);
        load_lds16(xh + aoff + 64 * DIM + k0, &Ah[2048 + w * 512]);
        load_lds16(xl + aoff + k0,            &Al[w * 512]);
        load_lds16(xl + aoff + 64 * DIM + k0, &Al[2048 + w * 512]);
        load_lds16(Wh + boff + k0,            &Bh[w * 512]);
        load_lds16(Wh + boff + 64 * DIM + k0, &Bh[2048 + w * 512]);
        load_lds16(Wl + boff + k0,            &Bl[w * 512]);
        load_lds16(Wl + boff + 64 * DIM + k0, &Bl[2048 + w * 512]);
        __syncthreads();

        bf16x8 fah[4], fal[4], fbh[4], fbl[4];
        #pragma unroll
        for (int mf = 0; mf < 4; ++mf) {
            const int r = rbA + mf * 16;
            const int off = r * 32 + (kh ^ ((r >> 1) & 3)) * 8;
            fah[mf] = *reinterpret_cast<const bf16x8*>(&Ah[off]);
            fal[mf] = *reinterpret_cast<const bf16x8*>(&Al[off]);
        }
        #pragma unroll
        for (int nf = 0; nf < 4; ++nf) {
            const int r = rbB + nf * 16;
            const int off = r * 32 + (kh ^ ((r >> 1) & 3)) * 8;
            fbh[nf] = *reinterpret_cast<const bf16x8*>(&Bh[off]);
            fbl[nf] = *reinterpret_cast<const bf16x8*>(&Bl[off]);
        }
        #pragma unroll
        for (int mf = 0; mf < 4; ++mf)
            #pragma unroll
            for (int nf = 0; nf < 4; ++nf) {
                acc[mf][nf] = __builtin_amdgcn_mfma_f32_16x16x32_bf16(fah[mf], fbh[nf], acc[mf][nf], 0, 0, 0);
                acc[mf][nf] = __builtin_amdgcn_mfma_f32_16x16x32_bf16(fal[mf], fbh[nf], acc[mf][nf], 0, 0, 0);
                acc[mf][nf] = __builtin_amdgcn_mfma_f32_16x16x32_bf16(fah[mf], fbl[nf], acc[mf][nf], 0, 0, 0);
            }
        __syncthreads();
    }

    #pragma unroll
    for (int mf = 0; mf < 4; ++mf)
        #pragma unroll
        for (int nf = 0; nf < 4; ++nf) {
            float* cp = C + (size_t)(row0 + wr * 64 + mf * 16 + (lane >> 4) * 4) * DIM
                          + col0 + wc * 64 + nf * 16 + (lane & 15);
            #pragma unroll
            for (int j = 0; j < 4; ++j)
                cp[(size_t)j * DIM] = acc[mf][nf][j];
        }
}

// ---------------------------------------------------------------------------
// fallback fp32 GEMM (round-1, proven)
#define BM 64
#define BN 64
#define BKD 32
__global__ __launch_bounds__(256) void gemm_qkv(
    const float* __restrict__ x,
    const float* __restrict__ Wq, const float* __restrict__ Wk, const float* __restrict__ Wv,
    float* __restrict__ Q, float* __restrict__ K, float* __restrict__ V)
{
    const float* W;
    float* C;
    if (blockIdx.z == 0)      { W = Wq; C = Q; }
    else if (blockIdx.z == 1) { W = Wk; C = K; }
    else                      { W = Wv; C = V; }

    __shared__ float As[BKD][BM];
    __shared__ float Bs[BKD][BN];

    const int tid  = threadIdx.x;
    const int row0 = blockIdx.x * BM;
    const int col0 = blockIdx.y * BN;
    const int ty   = tid >> 4;
    const int tx   = tid & 15;
    const int lrow = tid >> 3;
    const int lkq  = tid & 7;

    float acc[4][4] = {};
    for (int k0 = 0; k0 < DIM; k0 += BKD) {
        #pragma unroll
        for (int h = 0; h < 2; ++h) {
            const int arow = lrow + h * 32;
            float4 va = *reinterpret_cast<const float4*>(&x[(size_t)(row0 + arow) * DIM + k0 + lkq * 4]);
            As[lkq * 4 + 0][arow] = va.x; As[lkq * 4 + 1][arow] = va.y;
            As[lkq * 4 + 2][arow] = va.z; As[lkq * 4 + 3][arow] = va.w;
            float4 vb = *reinterpret_cast<const float4*>(&W[(size_t)(col0 + arow) * DIM + k0 + lkq * 4]);
            Bs[lkq * 4 + 0][arow] = vb.x; Bs[lkq * 4 + 1][arow] = vb.y;
            Bs[lkq * 4 + 2][arow] = vb.z; Bs[lkq * 4 + 3][arow] = vb.w;
        }
        __syncthreads();
        #pragma unroll
        for (int kk = 0; kk < BKD; ++kk) {
            float4 a4 = *reinterpret_cast<const float4*>(&As[kk][ty * 4]);
            float4 b4 = *reinterpret_cast<const float4*>(&Bs[kk][tx * 4]);
            float af[4] = {a4.x, a4.y, a4.z, a4.w};
            float bf[4] = {b4.x, b4.y, b4.z, b4.w};
            #pragma unroll
            for (int i = 0; i < 4; ++i)
                #pragma unroll
                for (int j = 0; j < 4; ++j)
                    acc[i][j] += af[i] * bf[j];
        }
        __syncthreads();
    }
    #pragma unroll
    for (int i = 0; i < 4; ++i) {
        float4 o = make_float4(acc[i][0], acc[i][1], acc[i][2], acc[i][3]);
        *reinterpret_cast<float4*>(&C[(size_t)(row0 + ty * 4 + i) * DIM + col0 + tx * 4]) = o;
    }
}

// ---------------------------------------------------------------------------
// merged: blocks [0,2048) compute M (8 waves, 1 l per wave, samples unrolled x8,
// XCD-local b=bid&7); blocks [2048,2176) V-mean partials (512 thr, d=tid).
__global__ __launch_bounds__(512) void m_and_vp(
    const float* __restrict__ Q, const float* __restrict__ K,
    const float* __restrict__ V, const int* __restrict__ smp,
    float* __restrict__ M, float* __restrict__ P)
{
    const int bid = blockIdx.x;
    if (bid < 2048) {
        const int wv   = threadIdx.x >> 6;
        const int lane = threadIdx.x & 63;
        const int b    = bid & 7;
        const int l    = (bid >> 3) * 8 + wv;

        const float* qr = Q + ((size_t)b * LSEQ + l) * DIM;
        float4 q0 = *reinterpret_cast<const float4*>(&qr[lane * 8]);
        float4 q1 = *reinterpret_cast<const float4*>(&qr[lane * 8 + 4]);

        const int* sp = smp + l * SK;
        const float* Kb = K + (size_t)b * LSEQ * DIM;

        float mx = -1e30f, sm = 0.0f;
        for (int s = 0; s < SK; s += 8) {
            int4 i0 = *reinterpret_cast<const int4*>(sp + s);
            int4 i1 = *reinterpret_cast<const int4*>(sp + s + 4);
            const int id[8] = {i0.x, i0.y, i0.z, i0.w, i1.x, i1.y, i1.z, i1.w};
            float p[8];
            #pragma unroll
            for (int j = 0; j < 8; ++j) {
                const float* r = Kb + (size_t)id[j] * DIM + lane * 8;
                float4 u0 = *reinterpret_cast<const float4*>(r);
                float4 u1 = *reinterpret_cast<const float4*>(r + 4);
                p[j] = q0.x*u0.x + q0.y*u0.y + q0.z*u0.z + q0.w*u0.w
                     + q1.x*u1.x + q1.y*u1.y + q1.z*u1.z + q1.w*u1.w;
            }
            #pragma unroll
            for (int o = 32; o; o >>= 1) {
                #pragma unroll
                for (int j = 0; j < 8; ++j) p[j] += __shfl_xor(p[j], o, 64);
            }
            #pragma unroll
            for (int j = 0; j < 8; ++j) { mx = fmaxf(mx, p[j]); sm += p[j]; }
        }
        if (lane == 0) M[(size_t)b * LSEQ + l] = mx - sm * (1.0f / LSEQ);
    } else {
        const int j = bid - 2048;
        const int b = j & 7, c = j >> 3;
        const int d = threadIdx.x;
        const float* vp = V + ((size_t)b * LSEQ + c * 128) * DIM + d;
        float s = 0.0f;
        for (int r = 0; r < 128; ++r) s += vp[(size_t)r * DIM];
        P[(size_t)(b * 16 + c) * DIM + d] = s;
    }
}

// ---------------------------------------------------------------------------
// merged: blocks 0..7 per-batch top-40; blocks 8..15 V-mean reduce.
__global__ __launch_bounds__(512) void topk_vr(
    const float* __restrict__ M, const float* __restrict__ P,
    int* __restrict__ topidx, float* __restrict__ vmean)
{
    __shared__ float vals[LSEQ];
    __shared__ float wvv[8];
    __shared__ int   wii[8];

    if (blockIdx.x < 8) {
        const int b = blockIdx.x;
        const int tid  = threadIdx.x;
        const int lane = tid & 63;
        const int wave = tid >> 6;

        #pragma unroll
        for (int q = 0; q < 4; ++q) vals[tid + q * 512] = M[b * LSEQ + tid + q * 512];
        __syncthreads();

        for (int t = 0; t < NTOP; ++t) {
            float bv = -1e30f;
            int   bi = 0x7fffffff;
            #pragma unroll
            for (int q = 0; q < 4; ++q) {
                const int ii = tid + q * 512;
                const float v = vals[ii];
                if (v > bv) { bv = v; bi = ii; }
            }
            #pragma unroll
            for (int o = 32; o; o >>= 1) {
                float ov = __shfl_xor(bv, o, 64);
                int   oi = __shfl_xor(bi, o, 64);
                if (ov > bv || (ov == bv && oi < bi)) { bv = ov; bi = oi; }
            }
            if (lane == 0) { wvv[wave] = bv; wii[wave] = bi; }
            __syncthreads();
            if (wave == 0) {
                float fv = (lane < 8) ? wvv[lane] : -1e30f;
                int   fi = (lane < 8) ? wii[lane] : 0x7fffffff;
                #pragma unroll
                for (int o = 4; o; o >>= 1) {
                    float ov = __shfl_xor(fv, o, 64);
                    int   oi = __shfl_xor(fi, o, 64);
                    if (ov > fv || (ov == fv && oi < fi)) { fv = ov; fi = oi; }
                }
                if (lane == 0) {
                    topidx[b * NTOP + t] = fi;
                    vals[fi] = -1e30f;
                }
            }
            __syncthreads();
        }
    } else {
        const int b = blockIdx.x - 8;
        const int d = threadIdx.x;
        float s = 0.0f;
        #pragma unroll
        for (int c = 0; c < 16; ++c) s += P[(size_t)(b * 16 + c) * DIM + d];
        vmean[b * DIM + d] = s * (1.0f / LSEQ);
    }
}

__global__ __launch_bounds__(256) void fill_out(
    const float4* __restrict__ vmean4, float4* __restrict__ out4)
{
    const int f = blockIdx.x * 256 + threadIdx.x;
    const int d4 = f & 127;
    const int b  = f >> 18;
    out4[f] = vmean4[b * 128 + d4];
}

// ---------------------------------------------------------------------------
__global__ __launch_bounds__(256) void scores_kernel(
    const float* __restrict__ Q, const float* __restrict__ K,
    const int* __restrict__ topidx, float* __restrict__ S)
{
    const int b  = blockIdx.x & 7;
    const int lc = blockIdx.x >> 3;           // 64-key chunk, 0..31
    __shared__ float Qs[40 * 132];
    __shared__ float Ks[64 * 132];
    __shared__ int tix[NTOP];
    const int tid = threadIdx.x;
    const int lt  = tid & 31;
    const int ug  = tid >> 5;
    float acc[2][5] = {};

    if (tid < NTOP) tix[tid] = topidx[b * NTOP + tid];
    __syncthreads();

    for (int d0 = 0; d0 < DIM; d0 += 128) {
        for (int j = tid; j < 1280; j += 256) {
            const int u = j >> 5, d4 = j & 31;
            *reinterpret_cast<float4*>(&Qs[u * 132 + d4 * 4]) =
                *reinterpret_cast<const float4*>(&Q[((size_t)b * LSEQ + tix[u]) * DIM + d0 + d4 * 4]);
        }
        for (int j = tid; j < 2048; j += 256) {
            const int l = j >> 5, d4 = j & 31;
            *reinterpret_cast<float4*>(&Ks[l * 132 + d4 * 4]) =
                *reinterpret_cast<const float4*>(&K[((size_t)b * LSEQ + lc * 64 + l) * DIM + d0 + d4 * 4]);
        }
        __syncthreads();
        for (int d4 = 0; d4 < 32; ++d4) {
            float4 ka = *reinterpret_cast<const float4*>(&Ks[lt * 132 + d4 * 4]);
            float4 kb = *reinterpret_cast<const float4*>(&Ks[(lt + 32) * 132 + d4 * 4]);
            #pragma unroll
            for (int i = 0; i < 5; ++i) {
                float4 q = *reinterpret_cast<const float4*>(&Qs[(ug + i * 8) * 132 + d4 * 4]);
                acc[0][i] += q.x * ka.x + q.y * ka.y + q.z * ka.z + q.w * ka.w;
                acc[1][i] += q.x * kb.x + q.y * kb.y + q.z * kb.z + q.w * kb.w;
            }
        }
        __syncthreads();
    }
    const float scale = 0.044194173824159216f;
    #pragma unroll
    for (int i = 0; i < 5; ++i) {
        const int u = ug + i * 8;
        S[((size_t)(b * NTOP + u)) * LSEQ + lc * 64 + lt]      = acc[0][i] * scale;
        S[((size_t)(b * NTOP + u)) * LSEQ + lc * 64 + lt + 32] = acc[1][i] * scale;
    }
}

__global__ __launch_bounds__(256) void softmax_kernel(
    const float* __restrict__ S, float* __restrict__ Pt)
{
    const int row = blockIdx.x;
    const int b = row / NTOP, u = row % NTOP;
    __shared__ float red[4];
    const int tid  = threadIdx.x;
    const int lane = tid & 63;
    const int wave = tid >> 6;
    const float* sr = S + (size_t)row * LSEQ;

    float v[8];
    float mx = -1e30f;
    #pragma unroll
    for (int j = 0; j < 8; ++j) { v[j] = sr[tid + j * 256]; mx = fmaxf(mx, v[j]); }
    #pragma unroll
    for (int o = 32; o; o >>= 1) mx = fmaxf(mx, __shfl_xor(mx, o, 64));
    if (lane == 0) red[wave] = mx;
    __syncthreads();
    mx = fmaxf(fmaxf(red[0], red[1]), fmaxf(red[2], red[3]));
    __syncthreads();

    float s = 0.0f;
    #pragma unroll
    for (int j = 0; j < 8; ++j) { v[j] = __expf(v[j] - mx); s += v[j]; }
    #pragma unroll
    for (int o = 32; o; o >>= 1) s += __shfl_xor(s, o, 64);
    if (lane == 0) red[wave] = s;
    __syncthreads();
    const float rec = 1.0f / (red[0] + red[1] + red[2] + red[3]);

    #pragma unroll
    for (int j = 0; j < 8; ++j)
        Pt[((size_t)b * LSEQ + tid + j * 256) * NTOP + u] = v[j] * rec;
}

__global__ __launch_bounds__(512) void pv_partial(
    const float* __restrict__ Pt, const float* __restrict__ V, float* __restrict__ Ppart)
{
    const int b  = blockIdx.x & 7;
    const int lc = blockIdx.x >> 3;           // 0..15, 128 keys each
    const int d  = threadIdx.x;
    float part[NTOP] = {};
    for (int l = 0; l < 128; ++l) {
        const float v = V[((size_t)b * LSEQ + lc * 128 + l) * DIM + d];
        const float* ps = Pt + ((size_t)b * LSEQ + lc * 128 + l) * NTOP;
        #pragma unroll
        for (int u = 0; u < NTOP; ++u) part[u] = fmaf(ps[u], v, part[u]);
    }
    #pragma unroll
    for (int u = 0; u < NTOP; ++u)
        Ppart[(((size_t)(b * 16 + lc)) * NTOP + u) * DIM + d] = part[u];
}

__global__ __launch_bounds__(512) void pv_reduce(
    const float* __restrict__ Ppart, const int* __restrict__ topidx, float* __restrict__ out)
{
    const int row = blockIdx.x;
    const int b = row / NTOP, u = row % NTOP;
    const int d = threadIdx.x;
    float s = 0.0f;
    #pragma unroll
    for (int lc = 0; lc < 16; ++lc)
        s += Ppart[(((size_t)(b * 16 + lc)) * NTOP + u) * DIM + d];
    out[((size_t)b * LSEQ + topidx[row]) * DIM + d] = s;
}

// ---------------------------------------------------------------------------
// round-1 attention (fallback only)
__global__ __launch_bounds__(256) void att_kernel(
    const float* __restrict__ Q, const float* __restrict__ K, const float* __restrict__ V,
    const int* __restrict__ topidx, float* __restrict__ out)
{
    const int b = blockIdx.x / NTOP;
    const int u = blockIdx.x % NTOP;
    const int l0 = topidx[b * NTOP + u];

    __shared__ float p[LSEQ];
    __shared__ float redm[4];
    __shared__ float reds[4];

    const int tid  = threadIdx.x;
    const int lane = tid & 63;
    const int wave = tid >> 6;

    const float* qr = Q + ((size_t)b * LSEQ + l0) * DIM;
    float4 q0 = *reinterpret_cast<const float4*>(&qr[lane * 8]);
    float4 q1 = *reinterpret_cast<const float4*>(&qr[lane * 8 + 4]);
    const float scale = 0.044194173824159216f;

    for (int it = 0; it < 512; ++it) {
        const int l = wave * 512 + it;
        const float* kr = K + ((size_t)b * LSEQ + l) * DIM;
        float4 k0 = *reinterpret_cast<const float4*>(&kr[lane * 8]);
        float4 k1 = *reinterpret_cast<const float4*>(&kr[lane * 8 + 4]);
        float d = q0.x * k0.x + q0.y * k0.y + q0.z * k0.z + q0.w * k0.w
                + q1.x * k1.x + q1.y * k1.y + q1.z * k1.z + q1.w * k1.w;
        #pragma unroll
        for (int o = 32; o; o >>= 1) d += __shfl_xor(d, o, 64);
        if (lane == 0) p[l] = d * scale;
    }
    __syncthreads();

    float mx = -1e30f;
    for (int i = tid; i < LSEQ; i += 256) mx = fmaxf(mx, p[i]);
    #pragma unroll
    for (int o = 32; o; o >>= 1) mx = fmaxf(mx, __shfl_xor(mx, o, 64));
    if (lane == 0) redm[wave] = mx;
    __syncthreads();
    mx = fmaxf(fmaxf(redm[0], redm[1]), fmaxf(redm[2], redm[3]));

    float s = 0.0f;
    for (int i = tid; i < LSEQ; i += 256) {
        float e = __expf(p[i] - mx);
        s += e;
        p[i] = e;
    }
    #pragma unroll
    for (int o = 32; o; o >>= 1) s += __shfl_xor(s, o, 64);
    if (lane == 0) reds[wave] = s;
    __syncthreads();
    const float rec = 1.0f / (reds[0] + reds[1] + reds[2] + reds[3]);

    float s0 = 0.0f, s1 = 0.0f;
    const float* vp = V + (size_t)b * LSEQ * DIM;
    for (int l = 0; l < LSEQ; ++l) {
        const float w = p[l];
        s0 += w * vp[(size_t)l * DIM + tid];
        s1 += w * vp[(size_t)l * DIM + tid + 256];
    }
    float* orow = out + ((size_t)b * LSEQ + l0) * DIM;
    orow[tid]       = s0 * rec;
    orow[tid + 256] = s1 * rec;
}

// ---------------------------------------------------------------------------
extern "C" void kernel_launch(void* const* d_in, const int* in_sizes, int n_in,
                              void* d_out, int out_size, void* d_ws, size_t ws_size,
                              hipStream_t stream)
{
    const float* x   = (const float*)d_in[0];
    const float* Wq  = (const float*)d_in[1];
    const float* Wk  = (const float*)d_in[2];
    const float* Wv  = (const float*)d_in[3];
    const int*   smp = (const int*)d_in[4];
    float* out = (float*)d_out;

    const size_t NQKV = (size_t)BATCH * LSEQ * DIM;   // 8388608
    float* ws = (float*)d_ws;

    float* Q     = ws;
    float* K     = Q + NQKV;
    float* V     = K + NQKV;
    float* Mb    = V + NQKV;                 // 16384
    float* vmP   = Mb + BATCH * LSEQ;        // 65536
    float* vmean = vmP + BATCH * 16 * DIM;   // 4096
    float* S     = vmean + BATCH * DIM;      // 655360
    float* Pt    = S + (size_t)BATCH * NTOP * LSEQ;   // 655360
    float* Qsel  = Pt + (size_t)BATCH * NTOP * LSEQ;  // 163840 (reserved)
    float* Ppart = Qsel + (size_t)BATCH * NTOP * DIM; // 2621440
    int*   topidx = (int*)(Ppart + (size_t)BATCH * 16 * NTOP * DIM);
    ushort* xh = (ushort*)(topidx + BATCH * NTOP);
    ushort* xl = xh + NQKV;
    ushort* wh = xl + NQKV;
    ushort* wl = wh + (size_t)3 * DIM * DIM;
    const size_t need_fast = (size_t)((char*)(wl + (size_t)3 * DIM * DIM) - (char*)d_ws);
    const size_t need_mid  = (size_t)((char*)(topidx + BATCH * NTOP) - (char*)d_ws);

    const bool fast = ws_size >= need_fast;
    const bool mid  = ws_size >= need_mid;

    if (mid) {
        if (fast) {
            convert_all<<<8960, 256, 0, stream>>>(x, Wq, Wk, Wv, xh, xl, wh, wl);
            gemm_mfma<<<dim3(BATCH * LSEQ / 128, DIM / 128, 3), 256, 0, stream>>>(
                xh, xl, wh, wl, Q, K, V);
        } else {
            gemm_qkv<<<dim3(BATCH * LSEQ / BM, DIM / BN, 3), 256, 0, stream>>>(
                x, Wq, Wk, Wv, Q, K, V);
        }
        m_and_vp<<<2176, 512, 0, stream>>>(Q, K, V, smp, Mb, vmP);
        topk_vr<<<16, 512, 0, stream>>>(Mb, vmP, topidx, vmean);
        fill_out<<<(BATCH * LSEQ * DIM / 4) / 256, 256, 0, stream>>>(
            (const float4*)vmean, (float4*)out);
        scores_kernel<<<256, 256, 0, stream>>>(Q, K, topidx, S);
        softmax_kernel<<<BATCH * NTOP, 256, 0, stream>>>(S, Pt);
        pv_partial<<<128, 512, 0, stream>>>(Pt, V, Ppart);
        pv_reduce<<<BATCH * NTOP, 512, 0, stream>>>(Ppart, topidx, out);
    } else {
        float* Qf = ws;
        float* Kf = Qf + NQKV;
        float* Vf = Kf + NQKV;
        float* Mf = Vf + NQKV;
        int*   ti = (int*)(Mf + (size_t)BATCH * LSEQ);
        float* Pf = (float*)(ti + BATCH * NTOP);
        float* vm = Pf + (size_t)BATCH * 16 * DIM;

        gemm_qkv<<<dim3(BATCH * LSEQ / BM, DIM / BN, 3), 256, 0, stream>>>(
            x, Wq, Wk, Wv, Qf, Kf, Vf);
        m_and_vp<<<2176, 512, 0, stream>>>(Qf, Kf, Vf, smp, Mf, Pf);
        topk_vr<<<16, 512, 0, stream>>>(Mf, Pf, ti, vm);
        fill_out<<<(BATCH * LSEQ * DIM / 4) / 256, 256, 0, stream>>>(
            (const float4*)vm, (float4*)out);
        att_kernel<<<BATCH * NTOP, 256, 0, stream>>>(Qf, Kf, Vf, ti, out);
    }
}